// Round 18
// baseline (235.779 us; speedup 1.0000x reference)
//
#include <hip/hip_runtime.h>
#include <math.h>

// ---------------------------------------------------------------------------
// TreeEnergyLoss on MI355X.
// k_edges (softmax merged; chunked f64 edge distances via LDS-upsampled
// embeddings) -> k_redux (parallel fixed-order chunk sum -> dkeyG; zeroes all
// pipeline flags) -> k_mega (FUSED TAIL, 216 blocks x 1024t, 121KB LDS ->
// 1 block/CU -> all blocks co-resident -> spin-wait flags are deadlock-free):
//   blocks [0,32):   STRUCT  = Boruvka MST (single-sweep packed-key argmin,
//                    (dist_hi,edge) lexicographic == reference's stable
//                    Kruskal) + compacted Euler rooting (Wyllie) + packed
//                    int2 doubling tables; publishes tableDone[pidx].
//   blocks [32,72):  FCHAN forest-0 (one (batch,channel) each); waits
//                    tableDone; publishes faCnt[batch].
//   blocks [72,192): FCHAN forests-1..3 (divide-on-load); waits tableDone +
//                    faCnt==5; publishes fbCnt[forestxbatch].
//   blocks [192,216): LOSS partials; waits fbCnt==5; last block reduces.
// ---------------------------------------------------------------------------

#define HH 48
#define WW 48
#define NN (HH*WW)          // 2304 nodes
#define EHH (HH*(WW-1))     // 2256 horizontal edges
#define EEE (2*EHH)         // 4512 edges
#define BB 8
#define KK 4
#define TPB 256
#define TPE 512             // edges kernel
#define TPM 1024            // mega kernel
#define NPN 5               // nodes per thread in k_edges (ceil 2304/512)
#define NPLM 3              // nodes per lane in fchan role (ceil 2304/1024)
#define LVE (2*(NN-1))      // 4606 directed tree edges
#define NIPT ((NN+TPM-1)/TPM)   // 3 node items per thread
#define SENTN 0xFFFFu
#define MAXT 12             // 2^12 = 4096 > max possible depth (2303)

__device__ __forceinline__ void edge_uv(int e,int& u,int& v){
  if(e<EHH){ int r=e/(WW-1); int c=e-r*(WW-1); u=r*WW+c; v=u+1; }
  else     { int t=e-EHH; u=t; v=t+WW; }
}

__device__ __forceinline__ void pick_src(int f, const float* lowf, const float* hf1,
                                         const float* hf2, const float* hf3,
                                         const float*& src, int& sh, int& C){
  if(f==0){src=lowf; sh=192; C=3;}
  else if(f==1){src=hf1; sh=24; C=512;}
  else if(f==2){src=hf2; sh=12; C=512;}
  else        {src=hf3; sh=6;  C=512;}
}

// ---------------------------------------------------------------------------
// Edge-distance partials, with softmax blocks appended at the end of the grid.
__global__ __launch_bounds__(TPE) void k_edges(
  const float* __restrict__ lowf, const float* __restrict__ hf1,
  const float* __restrict__ hf2, const float* __restrict__ hf3,
  const float* __restrict__ preds, float* __restrict__ probf,
  double* __restrict__ pd_low, double* __restrict__ pd_hf, int nchunk)
{
  __shared__ float up[4*NN+64];   // 37120 B (pad: guarded-unused over-reads)
  __shared__ int   y0t[48], y1t[48];
  __shared__ float wyt[48];
  const int tid=threadIdx.x;
  const int nEB=8+24*nchunk;

  if(blockIdx.x>=nEB){            // ---- softmax blocks ----
    int t=(blockIdx.x-nEB)*TPE+tid;
    if(t<BB*NN){
      int b=t/NN, i=t-b*NN;
      const float* p=preds+(size_t)b*KK*NN+i;
      float x0=p[0],x1=p[NN],x2=p[2*NN],x3=p[3*NN];
      float mx=fmaxf(fmaxf(x0,x1),fmaxf(x2,x3));
      float e0=expf(x0-mx),e1=expf(x1-mx),e2=expf(x2-mx),e3=expf(x3-mx);
      float s=((e0+e1)+(e2+e3));
      float* q=probf+(size_t)b*KK*NN+i;
      q[0]=e0/s; q[NN]=e1/s; q[2*NN]=e2/s; q[3*NN]=e3/s;
    }
    return;
  }

  int pidx, chunk, hfidx=0;
  if(blockIdx.x<8){ pidx=blockIdx.x; chunk=0; }
  else { int t=blockIdx.x-8; hfidx=t/nchunk; chunk=t-hfidx*nchunk; pidx=8+hfidx; }
  const int f=pidx>>3, b=pidx&7;
  const float* src; int sh,C;
  pick_src(f,lowf,hf1,hf2,hf3,src,sh,C);
  const int shw=sh*sh;
  const float* srcb=src+(size_t)b*C*shw;
  const int cpc=(f==0)?3:(512/nchunk);
  const int c_begin=chunk*cpc;
  const int c_end=(c_begin+cpc<C)?(c_begin+cpc):C;

  if(tid<48){
    float sy=(float)sh/48.0f;
    float ys=fmaxf(((float)tid+0.5f)*sy-0.5f,0.0f);
    int y0=(int)ys; if(y0>sh-1) y0=sh-1;
    int y1=y0+1; if(y1>sh-1) y1=sh-1;
    y0t[tid]=y0; y1t[tid]=y1; wyt[tid]=ys-(float)y0;
  }

  double accH[NPN], accV[NPN];
  #pragma unroll
  for(int j=0;j<NPN;j++){ accH[j]=0.0; accV[j]=0.0; }

  for(int c0=c_begin;c0<c_end;c0+=4){
    const int nc=(c_end-c0<4)?(c_end-c0):4;
    __syncthreads();               // protect previous sub-stage reads (and table init)
    for(int i=tid;i<NN;i+=TPE){
      int r=i/WW, c=i-r*WW;
      int y0=y0t[r], y1=y1t[r]; float wy=wyt[r];
      int x0=y0t[c], x1=y1t[c]; float wx=wyt[c];
      float w00=(1.0f-wy)*(1.0f-wx), w01=(1.0f-wy)*wx;
      float w10=wy*(1.0f-wx),        w11=wy*wx;
      int o00=y0*sh+x0, o01=y0*sh+x1, o10=y1*sh+x0, o11=y1*sh+x1;
      const float* pl=srcb+(size_t)c0*shw;
      for(int cc=0;cc<nc;cc++){
        const float* p=pl+(size_t)cc*shw;
        up[cc*NN+i]=w00*p[o00]+w01*p[o01]+w10*p[o10]+w11*p[o11];
      }
    }
    __syncthreads();
    #pragma unroll
    for(int j=0;j<NPN;j++){
      int u=tid+j*TPE;
      if(u<NN){
        int r=u/WW, c=u-r*WW;
        bool hOK=(c<WW-1), vOK=(r<HH-1);
        for(int cc=0;cc<nc;cc++){
          const float* pu=up+cc*NN+u;
          float a=pu[0], b1=pu[1], c1=pu[WW];
          if(hOK){ double d=(double)a-(double)b1; accH[j]=fma(d,d,accH[j]); }
          if(vOK){ double d=(double)a-(double)c1; accV[j]=fma(d,d,accV[j]); }
        }
      }
    }
  }
  double* outp=(f==0)? pd_low+(size_t)pidx*EEE
                     : pd_hf+((size_t)hfidx*nchunk+chunk)*EEE;
  #pragma unroll
  for(int j=0;j<NPN;j++){
    int u=tid+j*TPE;
    if(u<NN){
      int r=u/WW, c=u-r*WW;
      if(c<WW-1) outp[r*(WW-1)+c]=accH[j];
      if(r<HH-1) outp[EHH+u]=accV[j];
    }
  }
}

// ---------------------------------------------------------------------------
// Parallel fixed-order chunk reduction: dkeyG[pidx][e].  Zeroes all flags.
// flagsG layout (ints): [0]=lossCnt, [1..32]=tableDone, [33..40]=faCnt,
//                       [41..64]=fbCnt.
__global__ __launch_bounds__(TPB) void k_redux(
  const double* __restrict__ pd_low, const double* __restrict__ pd_hf,
  int nchunk, double* __restrict__ dkeyG, int* __restrict__ flagsG)
{
  int t=blockIdx.x*TPB+threadIdx.x;
  if(t<65) flagsG[t]=0;
  if(t>=32*EEE) return;
  int pidx=t/EEE, e=t-pidx*EEE;
  double s;
  if(pidx<8) s=pd_low[(size_t)pidx*EEE+e];
  else {
    const double* p0=pd_hf+((size_t)(pidx-8)*nchunk)*EEE+e;
    s=0.0;
    for(int k=0;k<nchunk;k++) s+=p0[(size_t)k*EEE];
  }
  dkeyG[t]=s;
}

// ---------------------------------------------------------------------------
// FUSED TAIL.  121KB static LDS -> 1 block/CU; 216 blocks co-resident.
__global__ __launch_bounds__(TPM) void k_mega(
  const double* __restrict__ dkeyG, int* __restrict__ Tg,
  int2* __restrict__ apT, const float* __restrict__ probf,
  float* __restrict__ FA, float* __restrict__ FB,
  const float* __restrict__ rois, float* __restrict__ partials,
  const float* __restrict__ wt, float* __restrict__ out,
  int* __restrict__ flagsG)
{
  __shared__ __align__(16) char smem[123904];
  const int tid=threadIdx.x;
  const int bid=blockIdx.x;

  if(bid<32){
    // ==================== STRUCT role (pidx = bid) ====================
    unsigned long long* keyE =(unsigned long long*)(smem+0);     // [0,36096)
    unsigned char*      mstf =(unsigned char*)(smem+36096);      // [36096,40608)
    unsigned long long* best =(unsigned long long*)(smem+40608); // [40608,59040)
    int*                comp =(int*)(smem+59040);                // [59040,68256)
    unsigned short*     uEdg =(unsigned short*)(smem+68256);     // [68256,77280)
    int*                lnk  =(int*)(smem+77472);                // [77472,86688)
    float4*             adjw =(float4*)(smem+40608);             // alias
    unsigned char*      adjS =(unsigned char*)(smem+77472);      // alias
    int*                chunkS=(int*)(smem+79776);               // [79776,83872)
    unsigned int*       eA   =(unsigned int*)(smem+0);           // alias
    unsigned int*       eB   =(unsigned int*)(smem+18432);       // alias
    unsigned short*     uDE  =(unsigned short*)(smem+83872);     // [83872,93088)
    int*                nodeoff=(int*)(smem+93088);              // [93088,102308)
    int*                flags=(int*)(smem+123552);               // [123552,123568)
    int*                ancA =(int*)(smem+0);
    float*              prmA =(float*)(smem+9216);
    int*                ancB =(int*)(smem+18432);
    float*              prmB =(float*)(smem+27648);

    const int pidx=bid;
    const int f=pidx>>3;
    const float sigma=(f==0)?0.02f:1.0f;
    const double* p0=dkeyG+(size_t)pidx*EEE;
    const int lane=tid&63, wid=tid>>6;
    int2* apT0=apT+(size_t)pidx*MAXT*NN;

    // ---- phase A: Boruvka ----
    for(int e=tid;e<EEE;e+=TPM){
      int u,v; edge_uv(e,u,v);
      uEdg[e]=(unsigned short)u;
      keyE[e]=(((unsigned long long)__double_as_longlong(p0[e]))&~0x1FFFull)
              |(unsigned long long)e;
      mstf[e]=0;
    }
    for(int i=tid;i<NN;i+=TPM){ comp[i]=i; best[i]=~0ull; lnk[i]=i; }
    if(tid==0) flags[1]=0;
    __syncthreads();

    for(int round=0;round<20;++round){
      for(int i=tid;i<NN;i+=TPM) lnk[i]=i;
      for(int e=tid;e<EEE;e+=TPM){
        int u=uEdg[e]; int v=(e<EHH)?u+1:u+WW;
        int cu=comp[u], cv=comp[v];
        if(cu!=cv){
          unsigned long long k=keyE[e];
          atomicMin(&best[cu],k);
          atomicMin(&best[cv],k);
        }
      }
      __syncthreads();
      for(int i=tid;i<NN;i+=TPM){
        if(comp[i]==i && best[i]!=~0ull){
          int e=(int)(best[i]&0x1FFFull);
          int u=uEdg[e]; int v=(e<EHH)?u+1:u+WW;
          int cu=comp[u], cv=comp[v];
          int other=(cu==i)?cv:cu;
          bool mutual=((best[other]&0x1FFFull)==(unsigned long long)e);
          if(!mutual || other<i){ lnk[i]=other; mstf[e]=1; flags[1]=1; }
        }
      }
      __syncthreads();
      if(flags[1]==0) break;
      {
        volatile int* vl=lnk;
        for(int i=tid;i<NN;i+=TPM){
          int x=comp[i];
          int p=vl[x];
          int gp=vl[p];
          while(p!=gp){
            vl[x]=gp;
            x=p; p=gp; gp=vl[p];
          }
          comp[i]=p;
        }
      }
      for(int i=tid;i<NN;i+=TPM) best[i]=~0ull;
      if(tid==0) flags[1]=0;
      __syncthreads();
    }
    __syncthreads();

    for(int i=tid;i<NN;i+=TPM){
      int r=i/WW, c=i-r*WW;
      int mask=0; float4 w; w.x=0.0f; w.y=0.0f; w.z=0.0f; w.w=0.0f;
      if(c>0    && mstf[r*(WW-1)+c-1]){ mask|=1; w.x=expf(-(float)p0[r*(WW-1)+c-1]/sigma); }
      if(c<WW-1 && mstf[r*(WW-1)+c])  { mask|=2; w.y=expf(-(float)p0[r*(WW-1)+c]/sigma); }
      if(r>0    && mstf[EHH+i-WW])    { mask|=4; w.z=expf(-(float)p0[EHH+i-WW]/sigma); }
      if(r<HH-1 && mstf[EHH+i])       { mask|=8; w.w=expf(-(float)p0[EHH+i]/sigma); }
      adjw[i]=w;
      adjS[i]=(unsigned char)mask;
    }
    __syncthreads();

    // ---- phase B: compacted Euler rooting ----
    {
      const int base=tid*NIPT;
      int dg[NIPT], incl[NIPT]; int lsum=0;
      #pragma unroll
      for(int j=0;j<NIPT;j++){
        int i=base+j;
        dg[j]=(i<NN)?__popc((int)adjS[i]):0;
        lsum+=dg[j]; incl[j]=lsum;
      }
      int x=lsum;
      #pragma unroll
      for(int off=1;off<64;off<<=1){
        int y=__shfl_up(x,off,64);
        if(lane>=off) x+=y;
      }
      if(lane==63) chunkS[wid]=x;
      __syncthreads();
      if(wid==0 && lane<16){
        int w=chunkS[lane];
        #pragma unroll
        for(int off=1;off<16;off<<=1){
          int y=__shfl_up(w,off,64);
          if(lane>=off) w+=y;
        }
        chunkS[lane]=w;
      }
      __syncthreads();
      const int waveoff=(wid>0)?chunkS[wid-1]:0;
      const int myoff=x+waveoff-lsum;
      #pragma unroll
      for(int j=0;j<NIPT;j++){
        int i=base+j;
        if(i<NN) nodeoff[i]=myoff+incl[j]-dg[j];
      }
    }
    __syncthreads();

    for(int u=tid;u<NN;u+=TPM){
      int mu=adjS[u];
      int off=nodeoff[u];
      int m=mu;
      while(m){
        int d=__ffs(m)-1; m&=m-1;
        int ce=off+__popc(mu&((1<<d)-1));
        int v=(d==0)?u-1:(d==1)?u+1:(d==2)?u-WW:u+WW;
        int rd=d^1;
        int mv=adjS[v];
        int nd=rd;
        #pragma unroll
        for(int k2=4;k2>=1;k2--){ int dd=(rd+k2)&3; if(mv&(1<<dd)) nd=dd; }
        int ne=nodeoff[v]+__popc(mv&((1<<nd)-1));
        unsigned int nxt=(ne==0)?SENTN:(unsigned int)ne;
        uDE[ce]=(unsigned short)((u<<2)|d);
        eA[ce]=(nxt<<16)|1u;
      }
    }
    __syncthreads();

    unsigned int* P=eA; unsigned int* Q=eB;
    for(int r2=0;r2<13;r2++){
      for(int t=tid;t<LVE;t+=TPM){
        unsigned int pk=P[t];
        unsigned int dist=pk&0xFFFFu, nxt=pk>>16;
        if(nxt!=SENTN){
          unsigned int pk2=P[nxt];
          dist+=pk2&0xFFFFu;
          nxt=pk2>>16;
          pk=(nxt<<16)|dist;
        }
        Q[t]=pk;
      }
      __syncthreads();
      unsigned int* tmp=P; P=Q; Q=tmp;
    }

    if(tid==0) apT0[0]=make_int2(0,__float_as_int(0.0f));
    for(int t=tid;t<LVE;t+=TPM){
      int ud=uDE[t]; int u=ud>>2, d=ud&3;
      int v=(d==0)?u-1:(d==1)?u+1:(d==2)?u-WW:u+WW;
      int rce=nodeoff[v]+__popc(adjS[v]&((1<<(d^1))-1));
      unsigned int dist=P[t]&0xFFFFu, rdist=P[rce]&0xFFFFu;
      if(dist>rdist){
        float4 w4=adjw[u];
        float w=(d==0)?w4.x:(d==1)?w4.y:(d==2)?w4.z:w4.w;
        apT0[v]=make_int2(u,__float_as_int(w));
      }
    }
    __syncthreads();

    // ---- phase C: tables + early stop ----
    {
      for(int t=tid;t<MAXT;t+=TPM) chunkS[t]=0;
      int* aP=ancA; int* aQ=ancB; float* pP=prmA; float* pQ=prmB;
      for(int i=tid;i<NN;i+=TPM){
        int2 rec=apT0[i];
        aP[i]=rec.x; pP[i]=__int_as_float(rec.y);
      }
      __syncthreads();
      int T=MAXT;
      for(int t=1;t<MAXT;t++){
        int any=0;
        for(int i=tid;i<NN;i+=TPM){
          int a=aP[i];
          int a2=aP[a]; float pr=pP[i]*pP[a];
          aQ[i]=a2; pQ[i]=pr;
          apT0[(size_t)t*NN+i]=make_int2(a2,__float_as_int(pr));
          if(pr!=0.0f) any=1;
        }
        if(any) chunkS[t]=1;
        __syncthreads();
        if(chunkS[t]==0){ T=t; break; }
        { int* t1=aP; aP=aQ; aQ=t1; float* t2=pP; pP=pQ; pQ=t2; }
      }
      if(tid==0) Tg[pidx]=T;
    }
    __syncthreads();
    if(tid==0){ __threadfence(); atomicExch(&flagsG[1+pidx],1); }
    return;
  }

  if(bid<192){
    // ==================== FCHAN roles ====================
    float* S =(float*)smem;          // 9216 B
    float* Sb=(float*)(smem+9216);   // 9216 B
    int pidx, xb, c, dv; float* o;
    if(bid<72){ int k=bid-32; int pg=k/5; c=k%5; pidx=pg; xb=pg; dv=0;
                o=FA+(size_t)k*NN; }
    else      { int k=bid-72; int pg=k/5; c=k%5; pidx=8+pg; xb=pg&7; dv=1;
                o=FB+(size_t)k*NN; }
    // wait for table (and FA batch for dv=1)
    if(tid==0){
      while(atomicAdd(&flagsG[1+pidx],0)==0){}
      if(dv) while(atomicAdd(&flagsG[33+xb],0)<5){}
    }
    __syncthreads();
    __threadfence();
    const int T=Tg[pidx];
    const int2* apP=apT+(size_t)pidx*MAXT*NN;
    const float* X=dv? FA : probf;

    float wv[NPLM];
    #pragma unroll
    for(int j=0;j<NPLM;j++){
      int i=tid+j*TPM;
      if(i<NN){
        int2 ap0=apP[i];
        wv[j]=__int_as_float(ap0.y);
        float val=1.0f;
        if(c<4){
          if(dv){
            float inv=1.0f/X[((size_t)xb*5+4)*NN+i];
            val=X[((size_t)xb*5+c)*NN+i]*inv;
          } else {
            val=X[((size_t)xb*KK+c)*NN+i];
          }
        }
        S[i]=val;
      } else wv[j]=0.0f;
    }
    __syncthreads();

    for(int t=0;t<T;t++){
      float sn[NPLM]; int aj[NPLM]; float pj[NPLM];
      #pragma unroll
      for(int j=0;j<NPLM;j++){
        int i=tid+j*TPM;
        if(i<NN){
          int2 ap=apP[(size_t)t*NN+i];
          sn[j]=S[i]; aj[j]=ap.x; pj[j]=__int_as_float(ap.y);
        } else { sn[j]=0.0f; aj[j]=0; pj[j]=0.0f; }
      }
      __syncthreads();
      #pragma unroll
      for(int j=0;j<NPLM;j++){
        int i=tid+j*TPM;
        if(i<NN) atomicAdd(&S[aj[j]], pj[j]*sn[j]);
      }
      __syncthreads();
    }

    #pragma unroll
    for(int j=0;j<NPLM;j++){
      int i=tid+j*TPM;
      if(i<NN){ float fq=1.0f-wv[j]*wv[j]; Sb[i]=fq*S[i]; }
    }
    __syncthreads();

    float* Sp=Sb; float* Sq=S;
    for(int t=0;t<T;t++){
      float bn[NPLM];
      #pragma unroll
      for(int j=0;j<NPLM;j++){
        int i=tid+j*TPM;
        if(i<NN){
          int2 ap=apP[(size_t)t*NN+i];
          bn[j]=fmaf(__int_as_float(ap.y),Sp[ap.x],Sp[i]);
        } else bn[j]=0.0f;
      }
      __syncthreads();
      #pragma unroll
      for(int j=0;j<NPLM;j++){
        int i=tid+j*TPM;
        if(i<NN) Sq[i]=bn[j];
      }
      __syncthreads();
      { float* tmp=Sp; Sp=Sq; Sq=tmp; }
    }
    for(int i=tid;i<NN;i+=TPM) o[i]=Sp[i];
    __syncthreads();
    if(tid==0){
      __threadfence();
      if(dv) atomicAdd(&flagsG[41+(bid-72)/5],1);
      else   atomicAdd(&flagsG[33+(bid-32)/5],1);
    }
    return;
  }

  // ==================== LOSS role ====================
  {
    float* red=(float*)smem;          // 4096 B
    __shared__ int lastS;
    const int fb=bid-192;             // 0..23
    const int b=fb&7;
    if(tid==0){ while(atomicAdd(&flagsG[41+fb],0)<5){} }
    __syncthreads();
    __threadfence();
    const float* pb=probf+(size_t)b*KK*NN;
    float part=0.0f;
    for(int i=tid;i<NN;i+=TPM){
      int r=i/WW, c2=i-r*WW;
      float roi=rois[(size_t)b*(192*192)+(4*r)*192+(4*c2)];
      float inv=1.0f/FB[((size_t)fb*5+4)*NN+i];
      float s=fabsf(pb[i]      -FB[((size_t)fb*5+0)*NN+i]*inv)
            + fabsf(pb[NN+i]   -FB[((size_t)fb*5+1)*NN+i]*inv)
            + fabsf(pb[2*NN+i] -FB[((size_t)fb*5+2)*NN+i]*inv)
            + fabsf(pb[3*NN+i] -FB[((size_t)fb*5+3)*NN+i]*inv);
      part+=roi*s;
    }
    red[tid]=part; __syncthreads();
    for(int s2=TPM/2;s2>0;s2>>=1){ if(tid<s2) red[tid]+=red[tid+s2]; __syncthreads(); }
    if(tid==0){
      partials[fb]=red[0];
      __threadfence();
      int old=atomicAdd(&flagsG[0],1);
      lastS=(old==3*BB-1);
    }
    __syncthreads();
    if(!lastS) return;

    float n=0.0f;
    for(int t=tid;t<BB*NN;t+=TPM){
      int b2=t/NN, i=t-b2*NN; int r=i/WW, c=i-r*WW;
      n += rois[(size_t)b2*(192*192)+(4*r)*192+(4*c)];
    }
    red[tid]=n; __syncthreads();
    for(int s=TPM/2;s>0;s>>=1){ if(tid<s) red[tid]+=red[tid+s]; __syncthreads(); }
    if(tid==0){
      float loss=0.0f;
      for(int j=0;j<3*BB;j++) loss+=partials[j];
      float N=red[0];
      out[0]=wt[0]*((N>0.0f)?(loss/N):loss);
    }
  }
}

// ---------------------------------------------------------------------------
extern "C" void kernel_launch(void* const* d_in, const int* in_sizes, int n_in,
                              void* d_out, int out_size, void* d_ws, size_t ws_size,
                              hipStream_t stream) {
  (void)in_sizes; (void)n_in; (void)out_size;
  const float* preds=(const float*)d_in[0];
  const float* lowf =(const float*)d_in[1];
  const float* hf1  =(const float*)d_in[2];
  const float* hf2  =(const float*)d_in[3];
  const float* hf3  =(const float*)d_in[4];
  const float* rois =(const float*)d_in[5];
  const float* wt   =(const float*)d_in[6];
  float* out=(float*)d_out;

  char* ws=(char*)d_ws;
  int*   flagsG=(int*)ws;                                      // 65 ints @0 (pad 512)
  float* partials=(float*)(ws+512);                            // 24 floats
  float* probf=(float*)(ws+768);                               // 294,912 B
  size_t tg_off=768+(size_t)BB*KK*NN*4;                        // 295,680
  int*   Tg=(int*)(ws+tg_off);                                 // 32 ints (pad 256)
  size_t dk_off=tg_off+256;                                    // 295,936 (8-mult)
  double* dkeyG=(double*)(ws+dk_off);                          // 1,155,072 B
  size_t pl_off=dk_off+(size_t)32*EEE*8;                       // 1,451,008
  double* pd_low=(double*)(ws+pl_off);                         // 288,768 B
  size_t ph_off=pl_off+(size_t)8*EEE*8;                        // 1,739,776
  double* pd_hf=(double*)(ws+ph_off);                          // 24*nchunk*EEE*8

  // table/F buffers ALIAS pd_hf (dead after k_redux).
  int2*  apT=(int2*)(ws+ph_off);                               // 7,077,888 B
  float* FA =(float*)(ws+ph_off+(size_t)32*MAXT*NN*8);         // 40*NN*4
  float* FB =(float*)(ws+ph_off+(size_t)32*MAXT*NN*8+(size_t)40*NN*4); // 120*NN*4

  int nchunk=32;
  if(ph_off+(size_t)24*32*EEE*8>ws_size) nchunk=16;

  const int nEB=8+24*nchunk;
  const int nSM=(BB*NN+TPE-1)/TPE;    // softmax blocks appended to k_edges
  k_edges<<<nEB+nSM,TPE,0,stream>>>(lowf,hf1,hf2,hf3,preds,probf,pd_low,pd_hf,nchunk);
  k_redux<<<(32*EEE+TPB-1)/TPB,TPB,0,stream>>>(pd_low,pd_hf,nchunk,dkeyG,flagsG);
  k_mega<<<216,TPM,0,stream>>>(dkeyG,Tg,apT,probf,FA,FB,rois,partials,wt,out,flagsG);
}

// Round 19
// 205.331 us; speedup vs baseline: 1.1483x; 1.1483x over previous
//
#include <hip/hip_runtime.h>
#include <math.h>

// ---------------------------------------------------------------------------
// TreeEnergyLoss on MI355X.  (Best-known configuration, R16: 206.7 us.)
// k_edges (softmax merged; chunked f64 edge distances via LDS-upsampled
// embeddings) -> k_redux (parallel fixed-order chunk sum -> dkeyG; zeroes the
// loss completion counter) -> k_struct (FUSED: 1024t Boruvka MST, single-sweep
// packed-key argmin ((dist_hi,edge) lexicographic == reference's stable
// Kruskal order) + COMPACTED Euler-tour rooting via Wyllie over exactly
// 2(N-1) slots + packed int2 pointer-doubling level tables) -> k_fchan
// (one block per (problem,channel); forest-123 divides on load) -> k_loss
// (ROI-masked L1 partials + last-block final reduction).
// ---------------------------------------------------------------------------

#define HH 48
#define WW 48
#define NN (HH*WW)          // 2304 nodes
#define EHH (HH*(WW-1))     // 2256 horizontal edges
#define EEE (2*EHH)         // 4512 edges
#define BB 8
#define KK 4
#define TPB 256
#define TPE 512             // edges kernel
#define TPW 1024            // struct kernel
#define TPF 512             // fchan kernel
#define NPL 5               // nodes per lane in fchan (ceil 2304/512)
#define NPN 5               // nodes per thread in k_edges (ceil 2304/512)
#define LVE (2*(NN-1))      // 4606 directed tree edges
#define RIPT ((LVE+TPW-1)/TPW)  // 5 scan items per thread
#define NIPT ((NN+TPW-1)/TPW)   // 3 node items per thread
#define SENTN 0xFFFFu
#define MAXT 12             // 2^12 = 4096 > max possible depth (2303)

// per-problem structure record in ws (ints): node-indexed int4 (parent,w,depth,0) | maxdepth
#define SSTRIDE_W (4*NN+8)
#define PK_OFF 0
#define D_OFF (4*NN)

__device__ __forceinline__ void edge_uv(int e,int& u,int& v){
  if(e<EHH){ int r=e/(WW-1); int c=e-r*(WW-1); u=r*WW+c; v=u+1; }
  else     { int t=e-EHH; u=t; v=t+WW; }
}

__device__ __forceinline__ void pick_src(int f, const float* lowf, const float* hf1,
                                         const float* hf2, const float* hf3,
                                         const float*& src, int& sh, int& C){
  if(f==0){src=lowf; sh=192; C=3;}
  else if(f==1){src=hf1; sh=24; C=512;}
  else if(f==2){src=hf2; sh=12; C=512;}
  else        {src=hf3; sh=6;  C=512;}
}

// ---------------------------------------------------------------------------
// Edge-distance partials, with softmax blocks appended at the end of the grid.
__global__ __launch_bounds__(TPE) void k_edges(
  const float* __restrict__ lowf, const float* __restrict__ hf1,
  const float* __restrict__ hf2, const float* __restrict__ hf3,
  const float* __restrict__ preds, float* __restrict__ probf,
  double* __restrict__ pd_low, double* __restrict__ pd_hf, int nchunk)
{
  __shared__ float up[4*NN+64];   // 37120 B (pad: guarded-unused over-reads)
  __shared__ int   y0t[48], y1t[48];
  __shared__ float wyt[48];
  const int tid=threadIdx.x;
  const int nEB=8+24*nchunk;

  if(blockIdx.x>=nEB){            // ---- softmax blocks ----
    int t=(blockIdx.x-nEB)*TPE+tid;
    if(t<BB*NN){
      int b=t/NN, i=t-b*NN;
      const float* p=preds+(size_t)b*KK*NN+i;
      float x0=p[0],x1=p[NN],x2=p[2*NN],x3=p[3*NN];
      float mx=fmaxf(fmaxf(x0,x1),fmaxf(x2,x3));
      float e0=expf(x0-mx),e1=expf(x1-mx),e2=expf(x2-mx),e3=expf(x3-mx);
      float s=((e0+e1)+(e2+e3));
      float* q=probf+(size_t)b*KK*NN+i;
      q[0]=e0/s; q[NN]=e1/s; q[2*NN]=e2/s; q[3*NN]=e3/s;
    }
    return;
  }

  int pidx, chunk, hfidx=0;
  if(blockIdx.x<8){ pidx=blockIdx.x; chunk=0; }
  else { int t=blockIdx.x-8; hfidx=t/nchunk; chunk=t-hfidx*nchunk; pidx=8+hfidx; }
  const int f=pidx>>3, b=pidx&7;
  const float* src; int sh,C;
  pick_src(f,lowf,hf1,hf2,hf3,src,sh,C);
  const int shw=sh*sh;
  const float* srcb=src+(size_t)b*C*shw;
  const int cpc=(f==0)?3:(512/nchunk);
  const int c_begin=chunk*cpc;
  const int c_end=(c_begin+cpc<C)?(c_begin+cpc):C;

  if(tid<48){
    float sy=(float)sh/48.0f;
    float ys=fmaxf(((float)tid+0.5f)*sy-0.5f,0.0f);
    int y0=(int)ys; if(y0>sh-1) y0=sh-1;
    int y1=y0+1; if(y1>sh-1) y1=sh-1;
    y0t[tid]=y0; y1t[tid]=y1; wyt[tid]=ys-(float)y0;
  }

  double accH[NPN], accV[NPN];
  #pragma unroll
  for(int j=0;j<NPN;j++){ accH[j]=0.0; accV[j]=0.0; }

  for(int c0=c_begin;c0<c_end;c0+=4){
    const int nc=(c_end-c0<4)?(c_end-c0):4;
    __syncthreads();               // protect previous sub-stage reads (and table init)
    for(int i=tid;i<NN;i+=TPE){
      int r=i/WW, c=i-r*WW;
      int y0=y0t[r], y1=y1t[r]; float wy=wyt[r];
      int x0=y0t[c], x1=y1t[c]; float wx=wyt[c];
      float w00=(1.0f-wy)*(1.0f-wx), w01=(1.0f-wy)*wx;
      float w10=wy*(1.0f-wx),        w11=wy*wx;
      int o00=y0*sh+x0, o01=y0*sh+x1, o10=y1*sh+x0, o11=y1*sh+x1;
      const float* pl=srcb+(size_t)c0*shw;
      for(int cc=0;cc<nc;cc++){
        const float* p=pl+(size_t)cc*shw;
        up[cc*NN+i]=w00*p[o00]+w01*p[o01]+w10*p[o10]+w11*p[o11];
      }
    }
    __syncthreads();
    #pragma unroll
    for(int j=0;j<NPN;j++){
      int u=tid+j*TPE;
      if(u<NN){
        int r=u/WW, c=u-r*WW;
        bool hOK=(c<WW-1), vOK=(r<HH-1);
        for(int cc=0;cc<nc;cc++){
          const float* pu=up+cc*NN+u;
          float a=pu[0], b1=pu[1], c1=pu[WW];
          if(hOK){ double d=(double)a-(double)b1; accH[j]=fma(d,d,accH[j]); }
          if(vOK){ double d=(double)a-(double)c1; accV[j]=fma(d,d,accV[j]); }
        }
      }
    }
  }
  double* outp=(f==0)? pd_low+(size_t)pidx*EEE
                     : pd_hf+((size_t)hfidx*nchunk+chunk)*EEE;
  #pragma unroll
  for(int j=0;j<NPN;j++){
    int u=tid+j*TPE;
    if(u<NN){
      int r=u/WW, c=u-r*WW;
      if(c<WW-1) outp[r*(WW-1)+c]=accH[j];
      if(r<HH-1) outp[EHH+u]=accV[j];
    }
  }
}

// ---------------------------------------------------------------------------
// Parallel fixed-order chunk reduction: dkeyG[pidx][e].  Zeroes loss counter.
__global__ __launch_bounds__(TPB) void k_redux(
  const double* __restrict__ pd_low, const double* __restrict__ pd_hf,
  int nchunk, double* __restrict__ dkeyG, int* __restrict__ cnt)
{
  int t=blockIdx.x*TPB+threadIdx.x;
  if(t==0) *cnt=0;
  if(t>=32*EEE) return;
  int pidx=t/EEE, e=t-pidx*EEE;
  double s;
  if(pidx<8) s=pd_low[(size_t)pidx*EEE+e];
  else {
    const double* p0=pd_hf+((size_t)(pidx-8)*nchunk)*EEE+e;
    s=0.0;
    for(int k=0;k<nchunk;k++) s+=p0[(size_t)k*EEE];
  }
  dkeyG[t]=s;
}

// ---------------------------------------------------------------------------
// FUSED structure kernel: Boruvka MST (single-sweep packed-key argmin) ->
// compacted Euler-tour rooting (Wyllie over exactly LVE slots; dense ids via
// degree prefix-sum, id(u,d) = nodeoff[u] + rank(d in mask)) -> packed int2
// pointer-doubling level tables.  One 1024-thread block per (forest,batch).
__global__ __launch_bounds__(TPW) void k_struct(
  const double* __restrict__ dkeyG, int* __restrict__ sbase,
  int2* __restrict__ apT)
{
  __shared__ __align__(16) char smem[123600];
  // phase A (Boruvka):
  unsigned long long* keyE =(unsigned long long*)(smem+0);     // [0,36096)
  unsigned char*      mstf =(unsigned char*)(smem+36096);      // [36096,40608)
  unsigned long long* best =(unsigned long long*)(smem+40608); // [40608,59040)
  int*                comp =(int*)(smem+59040);                // [59040,68256)
  unsigned short*     uEdg =(unsigned short*)(smem+68256);     // [68256,77280)
  int*                lnk  =(int*)(smem+77472);                // [77472,86688)
  // transition (over dead best/uEdg and lnk):
  float4*             adjw =(float4*)(smem+40608);             // [40608,77472)
  unsigned char*      adjS =(unsigned char*)(smem+77472);      // [77472,79776)
  int*                chunkS=(int*)(smem+79776);               // [79776,83872)
  // phase B (compacted root; over dead keyE/mstf and the tail region):
  unsigned int*       eA   =(unsigned int*)(smem+0);           // [0,18432)
  unsigned int*       eB   =(unsigned int*)(smem+18432);       // [18432,36864)
  unsigned short*     uDE  =(unsigned short*)(smem+83872);     // [83872,93088)
  int*                nodeoff=(int*)(smem+93088);              // [93088,102308)
  int*                flags=(int*)(smem+123552);               // [123552,123568)
  // phase C (tables; over dead eA/eB):
  int*                ancA =(int*)(smem+0);
  float*              prmA =(float*)(smem+9216);
  int*                ancB =(int*)(smem+18432);
  float*              prmB =(float*)(smem+27648);

  const int tid=threadIdx.x;
  const int pidx=blockIdx.x;
  const int f=pidx>>3;
  const float sigma=(f==0)?0.02f:1.0f;
  const double* p0=dkeyG+(size_t)pidx*EEE;
  const int lane=tid&63, wid=tid>>6;   // 16 waves

  // ================= phase A: Boruvka (single-sweep packed keys) ==========
  {
    for(int e=tid;e<EEE;e+=TPW){
      int u,v; edge_uv(e,u,v);
      uEdg[e]=(unsigned short)u;
      keyE[e]=(((unsigned long long)__double_as_longlong(p0[e]))&~0x1FFFull)
              |(unsigned long long)e;
      mstf[e]=0;
    }
    for(int i=tid;i<NN;i+=TPW){ comp[i]=i; best[i]=~0ull; lnk[i]=i; }
    if(tid==0) flags[1]=0;
    __syncthreads();

    for(int round=0;round<20;++round){
      for(int i=tid;i<NN;i+=TPW) lnk[i]=i;
      for(int e=tid;e<EEE;e+=TPW){
        int u=uEdg[e]; int v=(e<EHH)?u+1:u+WW;
        int cu=comp[u], cv=comp[v];
        if(cu!=cv){
          unsigned long long k=keyE[e];
          atomicMin(&best[cu],k);
          atomicMin(&best[cv],k);
        }
      }
      __syncthreads();
      // hook (mutual pair resolved toward smaller id; mutual => SAME edge, order strict)
      for(int i=tid;i<NN;i+=TPW){
        if(comp[i]==i && best[i]!=~0ull){
          int e=(int)(best[i]&0x1FFFull);
          int u=uEdg[e]; int v=(e<EHH)?u+1:u+WW;
          int cu=comp[u], cv=comp[v];
          int other=(cu==i)?cv:cu;
          bool mutual=((best[other]&0x1FFFull)==(unsigned long long)e);
          if(!mutual || other<i){ lnk[i]=other; mstf[e]=1; flags[1]=1; }
        }
      }
      __syncthreads();
      if(flags[1]==0) break;
      // find (lock-free path-halving) + next-round init (disjoint arrays)
      {
        volatile int* vl=lnk;
        for(int i=tid;i<NN;i+=TPW){
          int x=comp[i];
          int p=vl[x];
          int gp=vl[p];
          while(p!=gp){
            vl[x]=gp;
            x=p; p=gp; gp=vl[p];
          }
          comp[i]=p;
        }
      }
      for(int i=tid;i<NN;i+=TPW) best[i]=~0ull;
      if(tid==0) flags[1]=0;
      __syncthreads();
    }
    __syncthreads();

    // ---- transition: adjS (mask) + adjw (weights; true dist from global) --
    for(int i=tid;i<NN;i+=TPW){
      int r=i/WW, c=i-r*WW;
      int mask=0; float4 w; w.x=0.0f; w.y=0.0f; w.z=0.0f; w.w=0.0f;
      if(c>0    && mstf[r*(WW-1)+c-1]){ mask|=1; w.x=expf(-(float)p0[r*(WW-1)+c-1]/sigma); }
      if(c<WW-1 && mstf[r*(WW-1)+c])  { mask|=2; w.y=expf(-(float)p0[r*(WW-1)+c]/sigma); }
      if(r>0    && mstf[EHH+i-WW])    { mask|=4; w.z=expf(-(float)p0[EHH+i-WW]/sigma); }
      if(r<HH-1 && mstf[EHH+i])       { mask|=8; w.w=expf(-(float)p0[EHH+i]/sigma); }
      adjw[i]=w;
      adjS[i]=(unsigned char)mask;
    }
    if(tid==0) flags[2]=0;   // maxdepth accumulator
    __syncthreads();
  }

  // ================= phase B: compacted Euler-tour rooting ================
  {
    // ---- degree prefix-sum -> nodeoff (exclusive), wave-shfl scan ----
    {
      const int base=tid*NIPT;
      int dg[NIPT], incl[NIPT]; int lsum=0;
      #pragma unroll
      for(int j=0;j<NIPT;j++){
        int i=base+j;
        dg[j]=(i<NN)?__popc((int)adjS[i]):0;
        lsum+=dg[j]; incl[j]=lsum;
      }
      int x=lsum;
      #pragma unroll
      for(int off=1;off<64;off<<=1){
        int y=__shfl_up(x,off,64);
        if(lane>=off) x+=y;
      }
      if(lane==63) chunkS[wid]=x;
      __syncthreads();
      if(wid==0 && lane<16){
        int w=chunkS[lane];
        #pragma unroll
        for(int off=1;off<16;off<<=1){
          int y=__shfl_up(w,off,64);
          if(lane>=off) w+=y;
        }
        chunkS[lane]=w;
      }
      __syncthreads();
      const int waveoff=(wid>0)?chunkS[wid-1]:0;
      const int myoff=x+waveoff-lsum;
      #pragma unroll
      for(int j=0;j<NIPT;j++){
        int i=base+j;
        if(i<NN) nodeoff[i]=myoff+incl[j]-dg[j];
      }
    }
    __syncthreads();

    // ---- build compact successor list (id = nodeoff[u] + rank(d)) ----
    for(int u=tid;u<NN;u+=TPW){
      int mu=adjS[u];
      int off=nodeoff[u];
      int m=mu;
      while(m){
        int d=__ffs(m)-1; m&=m-1;
        int ce=off+__popc(mu&((1<<d)-1));
        int v=(d==0)?u-1:(d==1)?u+1:(d==2)?u-WW:u+WW;
        int rd=d^1;
        int mv=adjS[v];
        int nd=rd;
        #pragma unroll
        for(int k2=4;k2>=1;k2--){ int dd=(rd+k2)&3; if(mv&(1<<dd)) nd=dd; }
        int ne=nodeoff[v]+__popc(mv&((1<<nd)-1));
        unsigned int nxt=(ne==0)?SENTN:(unsigned int)ne;   // slot 0 == tour start
        uDE[ce]=(unsigned short)((u<<2)|d);
        eA[ce]=(nxt<<16)|1u;
      }
    }
    __syncthreads();

    // ---- Wyllie doubling: 13 rounds over LVE slots ----
    unsigned int* P=eA; unsigned int* Q=eB;
    for(int r2=0;r2<13;r2++){
      for(int t=tid;t<LVE;t+=TPW){
        unsigned int pk=P[t];
        unsigned int dist=pk&0xFFFFu, nxt=pk>>16;
        if(nxt!=SENTN){
          unsigned int pk2=P[nxt];
          dist+=pk2&0xFFFFu;
          nxt=pk2>>16;
          pk=(nxt<<16)|dist;
        }
        Q[t]=pk;
      }
      __syncthreads();
      unsigned int* tmp=P; P=Q; Q=tmp;
    }
    for(int t=tid;t<LVE;t+=TPW){
      unsigned int dist=P[t]&0xFFFFu;
      Q[t]=(unsigned int)(LVE-(int)dist);
    }
    __syncthreads();

    // ---- scatter +-1 into scan array (down iff pos < pos(reverse)) ----
    int* scanA=(int*)P;
    for(int t=tid;t<LVE;t+=TPW){
      unsigned int pos=Q[t];
      int ud=uDE[t]; int u=ud>>2, d=ud&3;
      int v=(d==0)?u-1:(d==1)?u+1:(d==2)?u-WW:u+WW;
      int rce=nodeoff[v]+__popc(adjS[v]&((1<<(d^1))-1));
      unsigned int rpos=Q[rce];
      scanA[pos]=(pos<rpos)?1:-1;
    }
    __syncthreads();

    // ---- blocked inclusive scan (wave-shfl; 2 barriers) ----
    const int base=tid*RIPT;
    int vals[RIPT]; int lsum=0;
    #pragma unroll
    for(int j=0;j<RIPT;j++){
      int p=base+j;
      int v=(p<LVE)?scanA[p]:0;
      lsum+=v; vals[j]=lsum;
    }
    int x=lsum;
    #pragma unroll
    for(int off=1;off<64;off<<=1){
      int y=__shfl_up(x,off,64);
      if(lane>=off) x+=y;
    }
    if(lane==63) chunkS[wid]=x;          // wave totals
    __syncthreads();
    if(wid==0 && lane<16){
      int w=chunkS[lane];
      #pragma unroll
      for(int off=1;off<16;off<<=1){
        int y=__shfl_up(w,off,64);
        if(lane>=off) w+=y;
      }
      chunkS[lane]=w;
    }
    __syncthreads();
    const int waveoff=(wid>0)?chunkS[wid-1]:0;
    const int myoff=x+waveoff-lsum;      // == sum of lsum for tid' < tid
    int mymax=0;
    #pragma unroll
    for(int j=0;j<RIPT;j++){
      int p=base+j;
      if(p<LVE){ int s=vals[j]+myoff; scanA[p]=s; if(s>mymax) mymax=s; }
    }
    if(mymax>0) atomicMax(&flags[2],mymax);
    __syncthreads();

    int* sp=sbase+(size_t)pidx*SSTRIDE_W;
    int4* g_pk=(int4*)(sp+PK_OFF);
    if(tid==0){
      g_pk[0]=make_int4(0,__float_as_int(0.0f),0,0);
      sp[D_OFF]=flags[2];
    }
    for(int t=tid;t<LVE;t+=TPW){
      unsigned int pos=Q[t];
      int ud=uDE[t]; int u=ud>>2, d=ud&3;
      int v=(d==0)?u-1:(d==1)?u+1:(d==2)?u-WW:u+WW;
      int rce=nodeoff[v]+__popc(adjS[v]&((1<<(d^1))-1));
      unsigned int rpos=Q[rce];
      if(pos<rpos){                       // down edge: u = parent(v)
        float4 w4=adjw[u];
        float w=(d==0)?w4.x:(d==1)?w4.y:(d==2)?w4.z:w4.w;
        g_pk[v]=make_int4(u,__float_as_int(w),scanA[pos],0);
      }
    }
    __syncthreads();   // g_pk visible to whole block (global, same-block sync)
  }

  // ================= phase C: packed level tables =================
  {
    const int* sp=sbase+(size_t)pidx*SSTRIDE_W;
    const int4* g_pk=(const int4*)(sp+PK_OFF);
    const int maxD=flags[2];
    int T=1; while((1<<T)<=maxD) T++;
    int2* gAP=apT+(size_t)pidx*MAXT*NN;
    int* aP=ancA; int* aQ=ancB; float* pP=prmA; float* pQ=prmB;
    for(int i=tid;i<NN;i+=TPW){
      int4 rec=g_pk[i];
      aP[i]=rec.x; pP[i]=__int_as_float(rec.y);
      gAP[i]=make_int2(rec.x,rec.y);
    }
    __syncthreads();
    for(int t=1;t<T;t++){
      for(int i=tid;i<NN;i+=TPW){
        int a=aP[i];
        int a2=aP[a]; float pr=pP[i]*pP[a];
        aQ[i]=a2; pQ[i]=pr;
        gAP[(size_t)t*NN+i]=make_int2(a2,__float_as_int(pr));
      }
      __syncthreads();
      { int* t1=aP; aP=aQ; aQ=t1; float* t2=pP; pP=pQ; pQ=t2; }
    }
  }
}

// ---------------------------------------------------------------------------
// Value-only tree filter, ONE (problem, channel) per block.
// dv=0: load X[(b*KK+c)*NN+i].  dv=1: load FA 5-stride, divide by channel 4.
__global__ __launch_bounds__(TPF) void k_fchan(
  const float* __restrict__ X, float* __restrict__ Fout,
  const int* __restrict__ sbase, const int2* __restrict__ apT,
  int pidx0, int dv)
{
  __shared__ float S[NN];    // 9216 B
  __shared__ float Sb[NN];   // 9216 B
  const int tid=threadIdx.x;
  const int pg=blockIdx.x/5, c=blockIdx.x%5;
  const int pidx=pidx0+pg;
  const int xb=pg&7;
  const int* sp=sbase+(size_t)pidx*SSTRIDE_W;
  const int4* g_pk=(const int4*)(sp+PK_OFF);
  const int maxD=sp[D_OFF];
  int T=1; while((1<<T)<=maxD) T++;
  const int2* apP=apT+(size_t)pidx*MAXT*NN;

  int dep[NPL]; float wv[NPL];
  #pragma unroll
  for(int j=0;j<NPL;j++){
    int i=tid+j*TPF;
    if(i<NN){
      int4 rec=g_pk[i];
      dep[j]=rec.z; wv[j]=__int_as_float(rec.y);
      float val=1.0f;
      if(c<4){
        if(dv){
          float inv=1.0f/X[((size_t)xb*5+4)*NN+i];
          val=X[((size_t)xb*5+c)*NN+i]*inv;
        } else {
          val=X[((size_t)xb*KK+c)*NN+i];
        }
      }
      S[i]=val;
    } else { dep[j]=-1; wv[j]=0.0f; }
  }
  __syncthreads();

  // ---- upward ----
  for(int t=0;t<T;t++){
    float sn[NPL]; int aj[NPL]; float pj[NPL];
    #pragma unroll
    for(int j=0;j<NPL;j++){
      int i=tid+j*TPF;
      if(i<NN){
        int2 ap=apP[(size_t)t*NN+i];
        sn[j]=S[i]; aj[j]=ap.x; pj[j]=__int_as_float(ap.y);
      }
      else { sn[j]=0.0f; aj[j]=0; pj[j]=0.0f; }
    }
    __syncthreads();
    int bit=1<<t;
    #pragma unroll
    for(int j=0;j<NPL;j++){
      if(dep[j]>=bit) atomicAdd(&S[aj[j]], pj[j]*sn[j]);
    }
    __syncthreads();
  }

  // ---- downward init: b = (1-w^2)*A_up (root w=0 -> b=A_up) ----
  #pragma unroll
  for(int j=0;j<NPL;j++){
    int i=tid+j*TPF;
    if(i<NN){ float fq=1.0f-wv[j]*wv[j]; Sb[i]=fq*S[i]; }
  }
  __syncthreads();

  // ---- downward rounds (copy-free ping-pong) ----
  float* Sp=Sb; float* Sq=S;
  for(int t=0;t<T;t++){
    float bn[NPL];
    #pragma unroll
    for(int j=0;j<NPL;j++){
      int i=tid+j*TPF;
      if(i<NN){
        int2 ap=apP[(size_t)t*NN+i];
        bn[j]=fmaf(__int_as_float(ap.y),Sp[ap.x],Sp[i]);
      } else bn[j]=0.0f;
    }
    __syncthreads();
    #pragma unroll
    for(int j=0;j<NPL;j++){
      int i=tid+j*TPF;
      if(i<NN) Sq[i]=bn[j];
    }
    __syncthreads();
    { float* tmp=Sp; Sp=Sq; Sq=tmp; }
  }
  // a == 0 for all nodes after T rounds (2^T > maxD) -> F = b
  float* o=Fout+(size_t)blockIdx.x*NN;
  for(int i=tid;i<NN;i+=TPF) o[i]=Sp[i];
}

// ---------------------------------------------------------------------------
// ROI-masked L1 partials; the LAST block to finish also does the final
// reduction (fence + counter; partials read in fixed order -> exact).
__global__ __launch_bounds__(TPB) void k_loss(
  const float* __restrict__ FB, const float* __restrict__ probf,
  const float* __restrict__ rois, float* __restrict__ partials,
  const float* __restrict__ wt, float* __restrict__ out, int* __restrict__ cnt)
{
  __shared__ float red[TPB];
  __shared__ int lastS;
  const int tid=threadIdx.x;
  const int fb=blockIdx.x;          // 0..23
  const int b=fb&7;
  const float* pb=probf+(size_t)b*KK*NN;
  float part=0.0f;
  for(int i=tid;i<NN;i+=TPB){
    int r=i/WW, c2=i-r*WW;
    float roi=rois[(size_t)b*(192*192)+(4*r)*192+(4*c2)];
    float inv=1.0f/FB[((size_t)fb*5+4)*NN+i];
    float s=fabsf(pb[i]      -FB[((size_t)fb*5+0)*NN+i]*inv)
          + fabsf(pb[NN+i]   -FB[((size_t)fb*5+1)*NN+i]*inv)
          + fabsf(pb[2*NN+i] -FB[((size_t)fb*5+2)*NN+i]*inv)
          + fabsf(pb[3*NN+i] -FB[((size_t)fb*5+3)*NN+i]*inv);
    part+=roi*s;
  }
  red[tid]=part; __syncthreads();
  for(int s2=TPB/2;s2>0;s2>>=1){ if(tid<s2) red[tid]+=red[tid+s2]; __syncthreads(); }
  if(tid==0){
    partials[fb]=red[0];
    __threadfence();
    int old=atomicAdd(cnt,1);
    lastS=(old==3*BB-1);
  }
  __syncthreads();
  if(!lastS) return;

  // ---- final reduction ----
  float n=0.0f;
  for(int t=tid;t<BB*NN;t+=TPB){
    int b2=t/NN, i=t-b2*NN; int r=i/WW, c=i-r*WW;
    n += rois[(size_t)b2*(192*192)+(4*r)*192+(4*c)];
  }
  red[tid]=n; __syncthreads();
  for(int s=TPB/2;s>0;s>>=1){ if(tid<s) red[tid]+=red[tid+s]; __syncthreads(); }
  if(tid==0){
    float loss=0.0f;
    for(int j=0;j<3*BB;j++) loss+=partials[j];
    float N=red[0];
    out[0]=wt[0]*((N>0.0f)?(loss/N):loss);
  }
}

// ---------------------------------------------------------------------------
extern "C" void kernel_launch(void* const* d_in, const int* in_sizes, int n_in,
                              void* d_out, int out_size, void* d_ws, size_t ws_size,
                              hipStream_t stream) {
  (void)in_sizes; (void)n_in; (void)out_size;
  const float* preds=(const float*)d_in[0];
  const float* lowf =(const float*)d_in[1];
  const float* hf1  =(const float*)d_in[2];
  const float* hf2  =(const float*)d_in[3];
  const float* hf3  =(const float*)d_in[4];
  const float* rois =(const float*)d_in[5];
  const float* wt   =(const float*)d_in[6];
  float* out=(float*)d_out;

  char* ws=(char*)d_ws;
  float* partials=(float*)ws;                                  // 24 floats @0
  int*   cnt=(int*)(ws+128);                                   // completion counter
  float* probf=(float*)(ws+256);                               // 294,912 B
  size_t sb_off=256+(size_t)2*BB*KK*NN*4;                      // 590,080
  int*   sbase=(int*)(ws+sb_off);                              // 1,180,672 B
  size_t dk_off=sb_off+(size_t)32*SSTRIDE_W*4;                 // 1,770,752 (8-mult)
  double* dkeyG=(double*)(ws+dk_off);                          // 1,155,072 B
  size_t pl_off=dk_off+(size_t)32*EEE*8;                       // 2,925,824
  double* pd_low=(double*)(ws+pl_off);                         // 288,768 B
  size_t ph_off=pl_off+(size_t)8*EEE*8;                        // 3,214,592
  double* pd_hf=(double*)(ws+ph_off);                          // 24*nchunk*EEE*8

  // table/F buffers ALIAS pd_hf (dead after k_redux); 8.55 MB <= 13.86 MB floor.
  int2*  apT=(int2*)(ws+ph_off);                               // 7,077,888 B
  float* FA =(float*)(ws+ph_off+(size_t)32*MAXT*NN*8);         // 40*NN*4
  float* FB =(float*)(ws+ph_off+(size_t)32*MAXT*NN*8+(size_t)40*NN*4); // 120*NN*4

  int nchunk=32;
  if(ph_off+(size_t)24*32*EEE*8>ws_size) nchunk=16;

  const int nEB=8+24*nchunk;
  const int nSM=(BB*NN+TPE-1)/TPE;    // softmax blocks appended to k_edges
  k_edges<<<nEB+nSM,TPE,0,stream>>>(lowf,hf1,hf2,hf3,preds,probf,pd_low,pd_hf,nchunk);
  k_redux<<<(32*EEE+TPB-1)/TPB,TPB,0,stream>>>(pd_low,pd_hf,nchunk,dkeyG,cnt);
  k_struct<<<32,TPW,0,stream>>>(dkeyG,sbase,apT);
  k_fchan<<<40,TPF,0,stream>>>(probf,FA,sbase,apT,0,0);
  k_fchan<<<120,TPF,0,stream>>>(FA,FB,sbase,apT,8,1);
  k_loss<<<3*BB,TPB,0,stream>>>(FB,probf,rois,partials,wt,out,cnt);
}